// Round 1
// baseline (541.460 us; speedup 1.0000x reference)
//
#include <hip/hip_runtime.h>
#include <hip/hip_bf16.h>

#define N_NODES 50000
#define N_EDGES 800000
#define FEATS 128
#define HEADS 8

typedef __attribute__((ext_vector_type(8))) short bf16x8;
typedef __attribute__((ext_vector_type(4))) float f32x4;

__device__ __forceinline__ unsigned short f2bf(float f){
  unsigned u = __float_as_uint(f);
  u += 0x7FFF + ((u >> 16) & 1);           // RNE
  return (unsigned short)(u >> 16);
}
__device__ __forceinline__ float bf2f(unsigned h){
  return __uint_as_float(h << 16);
}

// ---------------- BN column stats: sums[4][128] = {sum_q, sq_q, sum_k, sq_k}
__global__ void bn_stats_kernel(const float* __restrict__ ftq, const float* __restrict__ ftk,
                                float* __restrict__ sums){
  __shared__ float red[4][FEATS];
  int tid = threadIdx.x;
  for (int i = tid; i < 4*FEATS; i += 256) ((float*)red)[i] = 0.f;
  __syncthreads();
  int c = tid & 127;
  int half = tid >> 7;
  float sq_=0.f, qq_=0.f, sk_=0.f, kk_=0.f;
  for (int r = blockIdx.x*2 + half; r < N_NODES; r += gridDim.x*2){
    float xq = ftq[(size_t)r*FEATS + c];
    float xk = ftk[(size_t)r*FEATS + c];
    sq_ += xq; qq_ += xq*xq; sk_ += xk; kk_ += xk*xk;
  }
  atomicAdd(&red[0][c], sq_);
  atomicAdd(&red[1][c], qq_);
  atomicAdd(&red[2][c], sk_);
  atomicAdd(&red[3][c], kk_);
  __syncthreads();
  if (tid < FEATS){
    atomicAdd(&sums[0*FEATS+tid], red[0][tid]);
    atomicAdd(&sums[1*FEATS+tid], red[1][tid]);
    atomicAdd(&sums[2*FEATS+tid], red[2][tid]);
    atomicAdd(&sums[3*FEATS+tid], red[3][tid]);
  }
}

// ---------------- fold BN into weights: Wb[m][o][i] = W[o][i]*scale[i] (bf16),
// bias'[m][o] = sum_i shift[i]*W[o][i] (+bq for m==0).  m: 0=q,1=v,2=k
__global__ void fold_kernel(const float* __restrict__ Wq, const float* __restrict__ bq,
                            const float* __restrict__ Wk, const float* __restrict__ Wv,
                            const float* __restrict__ gq, const float* __restrict__ bqn,
                            const float* __restrict__ gk, const float* __restrict__ bkn,
                            const float* __restrict__ sums,
                            unsigned short* __restrict__ Wb, float* __restrict__ bias){
  int wave = blockIdx.x*4 + (threadIdx.x >> 6);   // 0..383
  int lane = threadIdx.x & 63;
  int m = wave >> 7;          // 0,1,2
  int o = wave & 127;
  const float* Wsrc = (m==0) ? Wq : (m==1) ? Wv : Wk;
  const float* g   = (m==2) ? gk : gq;
  const float* bb  = (m==2) ? bkn : bqn;
  const float* s0  = (m==2) ? (sums + 2*FEATS) : sums;
  const float invN = 1.0f / (float)N_NODES;
  float acc = 0.f;
  unsigned short w2[2];
  int i0 = lane*2;
  #pragma unroll
  for (int t = 0; t < 2; t++){
    int i = i0 + t;
    float mean = s0[i]*invN;
    float var  = s0[FEATS+i]*invN - mean*mean;
    float rstd = rsqrtf(var + 1e-5f);
    float scale = g[i]*rstd;
    float shift = bb[i] - mean*scale;
    float w = Wsrc[o*FEATS + i];
    w2[t] = f2bf(w*scale);
    acc += shift*w;
  }
  unsigned pack = (unsigned)w2[0] | ((unsigned)w2[1] << 16);
  ((unsigned*)Wb)[(m*FEATS*FEATS + o*FEATS + i0) >> 1] = pack;
  #pragma unroll
  for (int off = 1; off < 64; off <<= 1) acc += __shfl_xor(acc, off);
  if (lane == 0) bias[m*FEATS + o] = acc + ((m==0) ? bq[o] : 0.f);
}

// ---------------- bf16 MFMA GEMM: Out[N,128](bf16) = X[N,128](f32->bf16) @ Wb^T + bias
#define GM 64
__global__ __launch_bounds__(256) void gemm_kernel(const float* __restrict__ X,
                                                   const unsigned short* __restrict__ Wb,
                                                   const float* __restrict__ bias,
                                                   unsigned short* __restrict__ Out){
  __shared__ unsigned short As[GM][136];     // pad 8 -> row stride 272B (16B-aligned, 2-way bank)
  __shared__ unsigned short Bs[FEATS][136];
  int tid = threadIdx.x;
  int row0 = blockIdx.x * GM;
  { // stage B (already bf16): 8192 dwords
    const unsigned* srcp = (const unsigned*)Wb;
    for (int idx = tid; idx < FEATS*FEATS/2; idx += 256){
      int n = idx >> 6;
      int kk = (idx & 63) * 2;
      *(unsigned*)&Bs[n][kk] = srcp[idx];
    }
  }
  { // stage A with f32->bf16 convert: 2048 float4
    for (int idx = tid; idx < GM*FEATS/4; idx += 256){
      int r = idx >> 5;
      int c4 = (idx & 31) * 4;
      int row = row0 + r;
      float4 xv = make_float4(0.f,0.f,0.f,0.f);
      if (row < N_NODES) xv = *(const float4*)(X + (size_t)row*FEATS + c4);
      unsigned p0 = (unsigned)f2bf(xv.x) | ((unsigned)f2bf(xv.y) << 16);
      unsigned p1 = (unsigned)f2bf(xv.z) | ((unsigned)f2bf(xv.w) << 16);
      *(unsigned*)&As[r][c4]   = p0;
      *(unsigned*)&As[r][c4+2] = p1;
    }
  }
  __syncthreads();
  int wave = tid >> 6, lane = tid & 63;
  int r0 = wave * 16;
  int mrow = lane & 15, quad = lane >> 4;
  f32x4 acc[8];
  #pragma unroll
  for (int i = 0; i < 8; i++) acc[i] = (f32x4){0.f,0.f,0.f,0.f};
  #pragma unroll
  for (int kt = 0; kt < 4; kt++){
    int kb = kt*32 + quad*8;
    bf16x8 a = *(bf16x8*)&As[r0 + mrow][kb];
    #pragma unroll
    for (int ct = 0; ct < 8; ct++){
      bf16x8 b = *(bf16x8*)&Bs[ct*16 + mrow][kb];
      acc[ct] = __builtin_amdgcn_mfma_f32_16x16x32_bf16(a, b, acc[ct], 0, 0, 0);
    }
  }
  #pragma unroll
  for (int ct = 0; ct < 8; ct++){
    int col = ct*16 + mrow;
    float bv = bias[col];
    #pragma unroll
    for (int v = 0; v < 4; v++){
      int row = row0 + r0 + quad*4 + v;
      if (row < N_NODES)
        Out[(size_t)row*FEATS + col] = f2bf(acc[ct][v] + bv);
    }
  }
}

// ---------------- per-edge gated score: e[E,8]
__global__ void edge_e_kernel(const unsigned short* __restrict__ qb,
                              const unsigned short* __restrict__ kb,
                              const int* __restrict__ src, const int* __restrict__ dst,
                              const float* __restrict__ attn, float* __restrict__ e_out){
  int lane = threadIdx.x & 63;
  int wave = blockIdx.x*4 + (threadIdx.x >> 6);
  int nw = gridDim.x*4;
  float a0 = attn[lane*2], a1 = attn[lane*2+1];
  for (int e = wave; e < N_EDGES; e += nw){
    int s = src[e], d = dst[e];
    unsigned qv = *(const unsigned*)(qb + (size_t)s*FEATS + lane*2);
    unsigned kv = *(const unsigned*)(kb + (size_t)d*FEATS + lane*2);
    float x0 = bf2f(qv & 0xffffu) + bf2f(kv & 0xffffu);
    float x1 = bf2f(qv >> 16)     + bf2f(kv >> 16);
    float t = a0/(1.f + __expf(-x0)) + a1/(1.f + __expf(-x1));
    t += __shfl_xor(t, 1); t += __shfl_xor(t, 2); t += __shfl_xor(t, 4);
    if ((lane & 7) == 0) e_out[(size_t)e*HEADS + (lane >> 3)] = t;
  }
}

// ---------------- CSR build
__global__ void hist_kernel(const int* __restrict__ dst, int* __restrict__ counts){
  int t = blockIdx.x*256 + threadIdx.x;
  if (t < N_EDGES) atomicAdd(&counts[dst[t]], 1);
}
__global__ void scan1_kernel(const int* __restrict__ counts, int* __restrict__ offsets,
                             int* __restrict__ bsums){
  __shared__ int s[256];
  int i = blockIdx.x*256 + threadIdx.x;
  int v = (i < N_NODES) ? counts[i] : 0;
  s[threadIdx.x] = v;
  __syncthreads();
  for (int d = 1; d < 256; d <<= 1){
    int t = (threadIdx.x >= d) ? s[threadIdx.x - d] : 0;
    __syncthreads();
    s[threadIdx.x] += t;
    __syncthreads();
  }
  if (i < N_NODES) offsets[i] = s[threadIdx.x] - v;   // exclusive
  if (threadIdx.x == 255) bsums[blockIdx.x] = s[255];
}
__global__ void scan2_kernel(const int* __restrict__ bsums, int* __restrict__ bscan,
                             int* __restrict__ offsets, int nblocks){
  __shared__ int s[256];
  int v = (threadIdx.x < nblocks) ? bsums[threadIdx.x] : 0;
  s[threadIdx.x] = v;
  __syncthreads();
  for (int d = 1; d < 256; d <<= 1){
    int t = (threadIdx.x >= d) ? s[threadIdx.x - d] : 0;
    __syncthreads();
    s[threadIdx.x] += t;
    __syncthreads();
  }
  if (threadIdx.x < nblocks) bscan[threadIdx.x] = s[threadIdx.x] - v;
  if (threadIdx.x == 255) offsets[N_NODES] = s[255];
}
__global__ void scan3_kernel(int* __restrict__ offsets, const int* __restrict__ bscan){
  int i = blockIdx.x*256 + threadIdx.x;
  if (i < N_NODES) offsets[i] += bscan[blockIdx.x];
}
__global__ void scatter_kernel(const int* __restrict__ dst, const int* __restrict__ offsets,
                               int* __restrict__ cursor, int* __restrict__ eids){
  int t = blockIdx.x*256 + threadIdx.x;
  if (t < N_EDGES){
    int d = dst[t];
    int p = atomicAdd(&cursor[d], 1);
    eids[offsets[d] + p] = t;
  }
}

// ---------------- per-dst-node softmax + weighted aggregation (atomic-free)
__global__ void node_agg_kernel(const float* __restrict__ e, const int* __restrict__ offsets,
                                const int* __restrict__ eids, const int* __restrict__ src,
                                const unsigned short* __restrict__ vb, float* __restrict__ out){
  int lane = threadIdx.x & 63;
  int n = blockIdx.x*4 + (threadIdx.x >> 6);
  if (n >= N_NODES) return;
  int off0 = offsets[n];
  int deg = offsets[n+1] - off0;
  float2* out2 = (float2*)(out + (size_t)n*FEATS);
  if (deg == 0){ out2[lane] = make_float2(0.f, 0.f); return; }
  int h = lane & 7, eslot = lane >> 3;
  float mv = -1e30f;
  for (int j = eslot; j < deg; j += 8){
    int eid = eids[off0 + j];
    mv = fmaxf(mv, e[(size_t)eid*HEADS + h]);
  }
  mv = fmaxf(mv, __shfl_xor(mv, 8));
  mv = fmaxf(mv, __shfl_xor(mv, 16));
  mv = fmaxf(mv, __shfl_xor(mv, 32));
  float sv = 0.f;
  for (int j = eslot; j < deg; j += 8){
    int eid = eids[off0 + j];
    sv += __expf(e[(size_t)eid*HEADS + h] - mv);
  }
  sv += __shfl_xor(sv, 8); sv += __shfl_xor(sv, 16); sv += __shfl_xor(sv, 32);
  int h2 = lane >> 3;                       // head owning output feats 2*lane, 2*lane+1
  float m2 = __shfl(mv, h2);
  float is2 = 1.f / __shfl(sv, h2);
  float acc0 = 0.f, acc1 = 0.f;
  for (int j = 0; j < deg; j++){
    int eid = eids[off0 + j];
    int sidx = src[eid];
    float a = __expf(e[(size_t)eid*HEADS + h2] - m2) * is2;
    unsigned vv = *(const unsigned*)(vb + (size_t)sidx*FEATS + lane*2);
    acc0 += a * bf2f(vv & 0xffffu);
    acc1 += a * bf2f(vv >> 16);
  }
  out2[lane] = make_float2(acc0, acc1);
}

extern "C" void kernel_launch(void* const* d_in, const int* in_sizes, int n_in,
                              void* d_out, int out_size, void* d_ws, size_t ws_size,
                              hipStream_t stream){
  (void)in_sizes; (void)n_in; (void)out_size; (void)ws_size;
  const float* ftq  = (const float*)d_in[0];
  const float* ftk  = (const float*)d_in[1];
  const int*   src  = (const int*)d_in[2];
  const int*   dst  = (const int*)d_in[3];
  const float* Wq   = (const float*)d_in[4];
  const float* bq   = (const float*)d_in[5];
  const float* Wk   = (const float*)d_in[6];
  const float* Wv   = (const float*)d_in[7];
  const float* attn = (const float*)d_in[8];
  const float* gq   = (const float*)d_in[9];
  const float* bqn  = (const float*)d_in[10];
  const float* gk   = (const float*)d_in[11];
  const float* bkn  = (const float*)d_in[12];

  char* ws = (char*)d_ws;
  int*   counts  = (int*)(ws + 0);            // 200000 B
  int*   cursor  = (int*)(ws + 200000);       // 200000 B
  float* sums    = (float*)(ws + 400000);     // 2048 B   (zeroed region ends at 402048)
  int*   offsets = (int*)(ws + 402048);       // 200004 B
  int*   bsums   = (int*)(ws + 602064);       // 1024 B
  int*   bscan   = (int*)(ws + 603088);       // 1024 B
  int*   eids    = (int*)(ws + 604112);       // 3.2e6 B
  unsigned short* Wb   = (unsigned short*)(ws + 3804112);  // 98304 B
  float* biasf   = (float*)(ws + 3902416);    // 1536 B
  unsigned short* qb = (unsigned short*)(ws + 3903952);    // 12.8e6 B
  unsigned short* kb = qb + (size_t)N_NODES*FEATS;
  unsigned short* vb = kb + (size_t)N_NODES*FEATS;
  float* e_buf = (float*)(ws + 3903952 + 3*(size_t)N_NODES*FEATS*2);  // 25.6e6 B
  float* out = (float*)d_out;

  hipMemsetAsync(ws, 0, 402048, stream);  // counts, cursor, bn sums

  hipLaunchKernelGGL(bn_stats_kernel, dim3(512), dim3(256), 0, stream, ftq, ftk, sums);
  hipLaunchKernelGGL(hist_kernel, dim3((N_EDGES+255)/256), dim3(256), 0, stream, dst, counts);
  hipLaunchKernelGGL(scan1_kernel, dim3(196), dim3(256), 0, stream, counts, offsets, bsums);
  hipLaunchKernelGGL(scan2_kernel, dim3(1), dim3(256), 0, stream, bsums, bscan, offsets, 196);
  hipLaunchKernelGGL(scan3_kernel, dim3(196), dim3(256), 0, stream, offsets, bscan);
  hipLaunchKernelGGL(scatter_kernel, dim3((N_EDGES+255)/256), dim3(256), 0, stream, dst, offsets, cursor, eids);
  hipLaunchKernelGGL(fold_kernel, dim3(96), dim3(256), 0, stream,
                     Wq, bq, Wk, Wv, gq, bqn, gk, bkn, sums, Wb, biasf);
  hipLaunchKernelGGL(gemm_kernel, dim3((N_NODES+GM-1)/GM), dim3(256), 0, stream,
                     ftq, Wb,                 biasf,           qb);
  hipLaunchKernelGGL(gemm_kernel, dim3((N_NODES+GM-1)/GM), dim3(256), 0, stream,
                     ftq, Wb + FEATS*FEATS,   biasf + FEATS,   vb);
  hipLaunchKernelGGL(gemm_kernel, dim3((N_NODES+GM-1)/GM), dim3(256), 0, stream,
                     ftk, Wb + 2*FEATS*FEATS, biasf + 2*FEATS, kb);
  hipLaunchKernelGGL(edge_e_kernel, dim3(2048), dim3(256), 0, stream,
                     qb, kb, src, dst, attn, e_buf);
  hipLaunchKernelGGL(node_agg_kernel, dim3((N_NODES+3)/4), dim3(256), 0, stream,
                     e_buf, offsets, eids, src, vb, out);
}

// Round 2
// 358.359 us; speedup vs baseline: 1.5109x; 1.5109x over previous
//
#include <hip/hip_runtime.h>
#include <hip/hip_bf16.h>

#define N_NODES 50000
#define N_EDGES 800000
#define FEATS 128
#define HEADS 8

typedef __attribute__((ext_vector_type(8))) short bf16x8;
typedef __attribute__((ext_vector_type(4))) float f32x4;

__device__ __forceinline__ unsigned short f2bf(float f){
  unsigned u = __float_as_uint(f);
  u += 0x7FFF + ((u >> 16) & 1);           // RNE
  return (unsigned short)(u >> 16);
}
__device__ __forceinline__ float bf2f(unsigned h){
  return __uint_as_float(h << 16);
}
__device__ __forceinline__ void unpack8(uint4 p, float* f){
  f[0]=bf2f(p.x & 0xffffu); f[1]=bf2f(p.x >> 16);
  f[2]=bf2f(p.y & 0xffffu); f[3]=bf2f(p.y >> 16);
  f[4]=bf2f(p.z & 0xffffu); f[5]=bf2f(p.z >> 16);
  f[6]=bf2f(p.w & 0xffffu); f[7]=bf2f(p.w >> 16);
}

// ---------------- BN column stats: sums[4][128] = {sum_q, sq_q, sum_k, sq_k}
__global__ void bn_stats_kernel(const float* __restrict__ ftq, const float* __restrict__ ftk,
                                float* __restrict__ sums){
  __shared__ float red[4][FEATS];
  int tid = threadIdx.x;
  for (int i = tid; i < 4*FEATS; i += 256) ((float*)red)[i] = 0.f;
  __syncthreads();
  int c = tid & 127;
  int half = tid >> 7;
  float sq_=0.f, qq_=0.f, sk_=0.f, kk_=0.f;
  for (int r = blockIdx.x*2 + half; r < N_NODES; r += gridDim.x*2){
    float xq = ftq[(size_t)r*FEATS + c];
    float xk = ftk[(size_t)r*FEATS + c];
    sq_ += xq; qq_ += xq*xq; sk_ += xk; kk_ += xk*kk_*0.f + xk*xk; // keep simple
  }
  // fix: the line above must be plain sums; rewrite cleanly
  kk_ = 0.f; sk_ = 0.f; sq_ = 0.f; qq_ = 0.f;
  for (int r = blockIdx.x*2 + half; r < N_NODES; r += gridDim.x*2){
    float xq = ftq[(size_t)r*FEATS + c];
    float xk = ftk[(size_t)r*FEATS + c];
    sq_ += xq; qq_ += xq*xq; sk_ += xk; kk_ += xk*xk;
  }
  atomicAdd(&red[0][c], sq_);
  atomicAdd(&red[1][c], qq_);
  atomicAdd(&red[2][c], sk_);
  atomicAdd(&red[3][c], kk_);
  __syncthreads();
  if (tid < FEATS){
    atomicAdd(&sums[0*FEATS+tid], red[0][tid]);
    atomicAdd(&sums[1*FEATS+tid], red[1][tid]);
    atomicAdd(&sums[2*FEATS+tid], red[2][tid]);
    atomicAdd(&sums[3*FEATS+tid], red[3][tid]);
  }
}

// ---------------- fold BN into weights (bf16 W', fp32 bias')
__global__ void fold_kernel(const float* __restrict__ Wq, const float* __restrict__ bq,
                            const float* __restrict__ Wk, const float* __restrict__ Wv,
                            const float* __restrict__ gq, const float* __restrict__ bqn,
                            const float* __restrict__ gk, const float* __restrict__ bkn,
                            const float* __restrict__ sums,
                            unsigned short* __restrict__ Wb, float* __restrict__ bias){
  int wave = blockIdx.x*4 + (threadIdx.x >> 6);   // 0..383
  int lane = threadIdx.x & 63;
  int m = wave >> 7;          // 0=q,1=v,2=k
  int o = wave & 127;
  const float* Wsrc = (m==0) ? Wq : (m==1) ? Wv : Wk;
  const float* g   = (m==2) ? gk : gq;
  const float* bb  = (m==2) ? bkn : bqn;
  const float* s0  = (m==2) ? (sums + 2*FEATS) : sums;
  const float invN = 1.0f / (float)N_NODES;
  float acc = 0.f;
  unsigned short w2[2];
  int i0 = lane*2;
  #pragma unroll
  for (int t = 0; t < 2; t++){
    int i = i0 + t;
    float mean = s0[i]*invN;
    float var  = s0[FEATS+i]*invN - mean*mean;
    float rstd = rsqrtf(var + 1e-5f);
    float scale = g[i]*rstd;
    float shift = bb[i] - mean*scale;
    float w = Wsrc[o*FEATS + i];
    w2[t] = f2bf(w*scale);
    acc += shift*w;
  }
  unsigned pack = (unsigned)w2[0] | ((unsigned)w2[1] << 16);
  ((unsigned*)Wb)[(m*FEATS*FEATS + o*FEATS + i0) >> 1] = pack;
  #pragma unroll
  for (int off = 1; off < 64; off <<= 1) acc += __shfl_xor(acc, off);
  if (lane == 0) bias[m*FEATS + o] = acc + ((m==0) ? bq[o] : 0.f);
}

// ---------------- bf16 MFMA GEMM (3 outputs via blockIdx.y)
#define GM 64
__global__ __launch_bounds__(256) void gemm3_kernel(const float* __restrict__ ftq,
                                                    const float* __restrict__ ftk,
                                                    const unsigned short* __restrict__ Wball,
                                                    const float* __restrict__ biasall,
                                                    unsigned short* __restrict__ qb,
                                                    unsigned short* __restrict__ vb,
                                                    unsigned short* __restrict__ kb){
  int m = blockIdx.y;
  const float* X = (m==2) ? ftk : ftq;
  const unsigned short* Wb = Wball + m*FEATS*FEATS;
  const float* bias = biasall + m*FEATS;
  unsigned short* Out = (m==0) ? qb : (m==1) ? vb : kb;

  __shared__ unsigned short As[GM][136];
  __shared__ unsigned short Bs[FEATS][136];
  int tid = threadIdx.x;
  int row0 = blockIdx.x * GM;
  { // stage B (already bf16)
    const unsigned* srcp = (const unsigned*)Wb;
    for (int idx = tid; idx < FEATS*FEATS/2; idx += 256){
      int n = idx >> 6;
      int kk = (idx & 63) * 2;
      *(unsigned*)&Bs[n][kk] = srcp[idx];
    }
  }
  { // stage A with f32->bf16 convert
    for (int idx = tid; idx < GM*FEATS/4; idx += 256){
      int r = idx >> 5;
      int c4 = (idx & 31) * 4;
      int row = row0 + r;
      float4 xv = make_float4(0.f,0.f,0.f,0.f);
      if (row < N_NODES) xv = *(const float4*)(X + (size_t)row*FEATS + c4);
      unsigned p0 = (unsigned)f2bf(xv.x) | ((unsigned)f2bf(xv.y) << 16);
      unsigned p1 = (unsigned)f2bf(xv.z) | ((unsigned)f2bf(xv.w) << 16);
      *(unsigned*)&As[r][c4]   = p0;
      *(unsigned*)&As[r][c4+2] = p1;
    }
  }
  __syncthreads();
  int wave = tid >> 6, lane = tid & 63;
  int r0 = wave * 16;
  int mrow = lane & 15, quad = lane >> 4;
  f32x4 acc[8];
  #pragma unroll
  for (int i = 0; i < 8; i++) acc[i] = (f32x4){0.f,0.f,0.f,0.f};
  #pragma unroll
  for (int kt = 0; kt < 4; kt++){
    int kbk = kt*32 + quad*8;
    bf16x8 a = *(bf16x8*)&As[r0 + mrow][kbk];
    #pragma unroll
    for (int ct = 0; ct < 8; ct++){
      bf16x8 b = *(bf16x8*)&Bs[ct*16 + mrow][kbk];
      acc[ct] = __builtin_amdgcn_mfma_f32_16x16x32_bf16(a, b, acc[ct], 0, 0, 0);
    }
  }
  #pragma unroll
  for (int ct = 0; ct < 8; ct++){
    int col = ct*16 + mrow;
    float bv = bias[col];
    #pragma unroll
    for (int v = 0; v < 4; v++){
      int row = row0 + r0 + quad*4 + v;
      if (row < N_NODES)
        Out[(size_t)row*FEATS + col] = f2bf(acc[ct][v] + bv);
    }
  }
}

// ---------------- CSR build
__global__ void hist_kernel(const int* __restrict__ dst, int* __restrict__ counts){
  int t = blockIdx.x*256 + threadIdx.x;
  if (t < N_EDGES) atomicAdd(&counts[dst[t]], 1);
}
__global__ void scan1_kernel(const int* __restrict__ counts, int* __restrict__ offsets,
                             int* __restrict__ bsums){
  __shared__ int s[256];
  int i = blockIdx.x*256 + threadIdx.x;
  int v = (i < N_NODES) ? counts[i] : 0;
  s[threadIdx.x] = v;
  __syncthreads();
  for (int d = 1; d < 256; d <<= 1){
    int t = (threadIdx.x >= d) ? s[threadIdx.x - d] : 0;
    __syncthreads();
    s[threadIdx.x] += t;
    __syncthreads();
  }
  if (i < N_NODES) offsets[i] = s[threadIdx.x] - v;   // exclusive
  if (threadIdx.x == 255) bsums[blockIdx.x] = s[255];
}
__global__ void scan2_kernel(const int* __restrict__ bsums, int* __restrict__ bscan,
                             int* __restrict__ offsets, int nblocks){
  __shared__ int s[256];
  int v = (threadIdx.x < nblocks) ? bsums[threadIdx.x] : 0;
  s[threadIdx.x] = v;
  __syncthreads();
  for (int d = 1; d < 256; d <<= 1){
    int t = (threadIdx.x >= d) ? s[threadIdx.x - d] : 0;
    __syncthreads();
    s[threadIdx.x] += t;
    __syncthreads();
  }
  if (threadIdx.x < nblocks) bscan[threadIdx.x] = s[threadIdx.x] - v;
  if (threadIdx.x == 255) offsets[N_NODES] = s[255];
}
__global__ void scan3_kernel(int* __restrict__ offsets, const int* __restrict__ bscan){
  int i = blockIdx.x*256 + threadIdx.x;
  if (i < N_NODES) offsets[i] += bscan[blockIdx.x];
}
__global__ void scatter_kernel(const int* __restrict__ dst, const int* __restrict__ src,
                               const int* __restrict__ offsets,
                               int* __restrict__ cursor, int* __restrict__ src_csr){
  int t = blockIdx.x*256 + threadIdx.x;
  if (t < N_EDGES){
    int d = dst[t];
    int p = atomicAdd(&cursor[d], 1);
    src_csr[offsets[d] + p] = src[t];
  }
}

// ---------------- fused per-dst-node: edge scores + softmax + weighted agg
// wave layout: 8 groups (g = lane>>3) x 8 heads (h = lane&7);
// group g handles edge j+g, lane owns head h = 16 feats = 32B of each row.
__global__ __launch_bounds__(256) void node_fused_kernel(
    const unsigned short* __restrict__ qb, const unsigned short* __restrict__ kb,
    const unsigned short* __restrict__ vb, const float* __restrict__ attn,
    const int* __restrict__ src_csr, const int* __restrict__ offsets,
    float* __restrict__ exe, float* __restrict__ out){
  int lane = threadIdx.x & 63;
  int n = blockIdx.x*4 + (threadIdx.x >> 6);
  if (n >= N_NODES) return;
  int h = lane & 7, g = lane >> 3;
  int off0 = offsets[n];
  int deg = offsets[n+1] - off0;
  if (deg == 0){
    ((float2*)(out + (size_t)n*FEATS))[lane] = make_float2(0.f, 0.f);
    return;
  }
  // per-lane constants: attn and k[n] for head h (16 feats)
  float ar[16], kf[16];
  {
    const uint4* ap = (const uint4*)(attn + h*16);   // 16 floats = 4 uint4
    uint4 a0 = ap[0], a1 = ap[1], a2 = ap[2], a3 = ap[3];
    ar[0]=__uint_as_float(a0.x); ar[1]=__uint_as_float(a0.y); ar[2]=__uint_as_float(a0.z); ar[3]=__uint_as_float(a0.w);
    ar[4]=__uint_as_float(a1.x); ar[5]=__uint_as_float(a1.y); ar[6]=__uint_as_float(a1.z); ar[7]=__uint_as_float(a1.w);
    ar[8]=__uint_as_float(a2.x); ar[9]=__uint_as_float(a2.y); ar[10]=__uint_as_float(a2.z); ar[11]=__uint_as_float(a2.w);
    ar[12]=__uint_as_float(a3.x); ar[13]=__uint_as_float(a3.y); ar[14]=__uint_as_float(a3.z); ar[15]=__uint_as_float(a3.w);
    const unsigned short* kr = kb + (size_t)n*FEATS + h*16;
    uint4 k0 = *(const uint4*)kr;
    uint4 k1 = *(const uint4*)(kr + 8);
    unpack8(k0, kf); unpack8(k1, kf+8);
  }
  size_t ebase = (size_t)off0*HEADS;
  // pass 1: e = sum attn*sigmoid(q+k) per head; ex = exp(e); sum ex per head.
  // (no max-subtraction: |e| <= sum|attn| ~ 25 -> exp safe in fp32)
  float ssum = 0.f;
  for (int j = 0; j < deg; j += 8){
    int je = j + g;
    float ex = 0.f;
    if (je < deg){
      int s = src_csr[off0 + je];
      const unsigned short* qr = qb + (size_t)s*FEATS + h*16;
      uint4 q0 = *(const uint4*)qr;
      uint4 q1 = *(const uint4*)(qr + 8);
      float qf[16]; unpack8(q0, qf); unpack8(q1, qf+8);
      float t = 0.f;
      #pragma unroll
      for (int i = 0; i < 16; i++){
        float x = qf[i] + kf[i];
        t += ar[i] * __builtin_amdgcn_rcpf(1.f + __expf(-x));
      }
      ex = __expf(t);
      exe[ebase + (size_t)je*HEADS + h] = ex;   // linear: ebase + j*8 + lane (coalesced)
    }
    ssum += ex;
  }
  ssum += __shfl_xor(ssum, 8); ssum += __shfl_xor(ssum, 16); ssum += __shfl_xor(ssum, 32);
  float inv_s = 1.f / ssum;
  // pass 2: out[n] = sum_e a * v[src]
  float acc[16];
  #pragma unroll
  for (int i = 0; i < 16; i++) acc[i] = 0.f;
  for (int j = 0; j < deg; j += 8){
    int je = j + g;
    if (je < deg){
      int s = src_csr[off0 + je];
      float a = exe[ebase + (size_t)je*HEADS + h] * inv_s;
      const unsigned short* vr = vb + (size_t)s*FEATS + h*16;
      uint4 v0 = *(const uint4*)vr;
      uint4 v1 = *(const uint4*)(vr + 8);
      float vf[16]; unpack8(v0, vf); unpack8(v1, vf+8);
      #pragma unroll
      for (int i = 0; i < 16; i++) acc[i] += a * vf[i];
    }
  }
  #pragma unroll
  for (int i = 0; i < 16; i++){
    acc[i] += __shfl_xor(acc[i], 8);
    acc[i] += __shfl_xor(acc[i], 16);
    acc[i] += __shfl_xor(acc[i], 32);
  }
  if (g == 0){
    float4* op = (float4*)(out + (size_t)n*FEATS + h*16);
    op[0] = make_float4(acc[0], acc[1], acc[2], acc[3]);
    op[1] = make_float4(acc[4], acc[5], acc[6], acc[7]);
    op[2] = make_float4(acc[8], acc[9], acc[10], acc[11]);
    op[3] = make_float4(acc[12], acc[13], acc[14], acc[15]);
  }
}

extern "C" void kernel_launch(void* const* d_in, const int* in_sizes, int n_in,
                              void* d_out, int out_size, void* d_ws, size_t ws_size,
                              hipStream_t stream){
  (void)in_sizes; (void)n_in; (void)out_size; (void)ws_size;
  const float* ftq  = (const float*)d_in[0];
  const float* ftk  = (const float*)d_in[1];
  const int*   src  = (const int*)d_in[2];
  const int*   dst  = (const int*)d_in[3];
  const float* Wq   = (const float*)d_in[4];
  const float* bq   = (const float*)d_in[5];
  const float* Wk   = (const float*)d_in[6];
  const float* Wv   = (const float*)d_in[7];
  const float* attn = (const float*)d_in[8];
  const float* gq   = (const float*)d_in[9];
  const float* bqn  = (const float*)d_in[10];
  const float* gk   = (const float*)d_in[11];
  const float* bkn  = (const float*)d_in[12];

  char* ws = (char*)d_ws;
  int*   counts  = (int*)(ws + 0);            // 200000 B
  int*   cursor  = (int*)(ws + 200000);       // 200000 B
  float* sums    = (float*)(ws + 400000);     // 2048 B (zero region ends 402048)
  int*   offsets = (int*)(ws + 402048);       // 200004 B
  int*   bsums   = (int*)(ws + 602064);       // pad to 603088
  int*   bscan   = (int*)(ws + 603088);       // 1024 B
  int*   src_csr = (int*)(ws + 604112);       // 3.2e6 B
  unsigned short* Wb   = (unsigned short*)(ws + 3804112);  // 98304 B
  float* biasf   = (float*)(ws + 3902416);    // 1536 B
  unsigned short* qb = (unsigned short*)(ws + 3903952);    // 12.8e6 B
  unsigned short* kb = qb + (size_t)N_NODES*FEATS;
  unsigned short* vb = kb + (size_t)N_NODES*FEATS;
  float* exe = (float*)(ws + 3903952 + 3*(size_t)N_NODES*FEATS*2);  // 25.6e6 B
  float* out = (float*)d_out;

  hipMemsetAsync(ws, 0, 402048, stream);  // counts, cursor, bn sums

  hipLaunchKernelGGL(bn_stats_kernel, dim3(512), dim3(256), 0, stream, ftq, ftk, sums);
  hipLaunchKernelGGL(hist_kernel, dim3((N_EDGES+255)/256), dim3(256), 0, stream, dst, counts);
  hipLaunchKernelGGL(scan1_kernel, dim3(196), dim3(256), 0, stream, counts, offsets, bsums);
  hipLaunchKernelGGL(scan2_kernel, dim3(1), dim3(256), 0, stream, bsums, bscan, offsets, 196);
  hipLaunchKernelGGL(scan3_kernel, dim3(196), dim3(256), 0, stream, offsets, bscan);
  hipLaunchKernelGGL(scatter_kernel, dim3((N_EDGES+255)/256), dim3(256), 0, stream,
                     dst, src, offsets, cursor, src_csr);
  hipLaunchKernelGGL(fold_kernel, dim3(96), dim3(256), 0, stream,
                     Wq, bq, Wk, Wv, gq, bqn, gk, bkn, sums, Wb, biasf);
  hipLaunchKernelGGL(gemm3_kernel, dim3((N_NODES+GM-1)/GM, 3), dim3(256), 0, stream,
                     ftq, ftk, Wb, biasf, qb, vb, kb);
  hipLaunchKernelGGL(node_fused_kernel, dim3((N_NODES+3)/4), dim3(256), 0, stream,
                     qb, kb, vb, attn, src_csr, offsets, exe, out);
}

// Round 3
// 319.780 us; speedup vs baseline: 1.6932x; 1.1206x over previous
//
#include <hip/hip_runtime.h>
#include <hip/hip_bf16.h>

#define N_NODES 50000
#define N_EDGES 800000
#define FEATS 128
#define HEADS 8

typedef __attribute__((ext_vector_type(8))) short bf16x8;
typedef __attribute__((ext_vector_type(4))) float f32x4;

__device__ __forceinline__ unsigned short f2bf(float f){
  unsigned u = __float_as_uint(f);
  u += 0x7FFF + ((u >> 16) & 1);           // RNE
  return (unsigned short)(u >> 16);
}
__device__ __forceinline__ float bf2f(unsigned h){
  return __uint_as_float(h << 16);
}
__device__ __forceinline__ void unpack8(uint4 p, float* f){
  f[0]=bf2f(p.x & 0xffffu); f[1]=bf2f(p.x >> 16);
  f[2]=bf2f(p.y & 0xffffu); f[3]=bf2f(p.y >> 16);
  f[4]=bf2f(p.z & 0xffffu); f[5]=bf2f(p.z >> 16);
  f[6]=bf2f(p.w & 0xffffu); f[7]=bf2f(p.w >> 16);
}

// ---------------- fused: BN column stats (blocks 0..511) + dst histogram (512..767)
__global__ void stats_hist_kernel(const float* __restrict__ ftq, const float* __restrict__ ftk,
                                  float* __restrict__ sums,
                                  const int* __restrict__ dst, int* __restrict__ counts){
  if (blockIdx.x < 512){
    __shared__ float red[4][FEATS];
    int tid = threadIdx.x;
    for (int i = tid; i < 4*FEATS; i += 256) ((float*)red)[i] = 0.f;
    __syncthreads();
    int c = tid & 127;
    int half = tid >> 7;
    float sq_=0.f, qq_=0.f, sk_=0.f, kk_=0.f;
    for (int r = blockIdx.x*2 + half; r < N_NODES; r += 512*2){
      float xq = ftq[(size_t)r*FEATS + c];
      float xk = ftk[(size_t)r*FEATS + c];
      sq_ += xq; qq_ += xq*xq; sk_ += xk; kk_ += xk*xk;
    }
    atomicAdd(&red[0][c], sq_);
    atomicAdd(&red[1][c], qq_);
    atomicAdd(&red[2][c], sk_);
    atomicAdd(&red[3][c], kk_);
    __syncthreads();
    if (tid < FEATS){
      atomicAdd(&sums[0*FEATS+tid], red[0][tid]);
      atomicAdd(&sums[1*FEATS+tid], red[1][tid]);
      atomicAdd(&sums[2*FEATS+tid], red[2][tid]);
      atomicAdd(&sums[3*FEATS+tid], red[3][tid]);
    }
  } else {
    int b = blockIdx.x - 512;   // 0..255
    for (int t = b*256 + threadIdx.x; t < N_EDGES; t += 256*256)
      atomicAdd(&counts[dst[t]], 1);
  }
}

// ---------------- block-level exclusive scan of counts
__global__ void scan1_kernel(const int* __restrict__ counts, int* __restrict__ offsets,
                             int* __restrict__ bsums){
  __shared__ int s[256];
  int i = blockIdx.x*256 + threadIdx.x;
  int v = (i < N_NODES) ? counts[i] : 0;
  s[threadIdx.x] = v;
  __syncthreads();
  for (int d = 1; d < 256; d <<= 1){
    int t = (threadIdx.x >= d) ? s[threadIdx.x - d] : 0;
    __syncthreads();
    s[threadIdx.x] += t;
    __syncthreads();
  }
  if (i < N_NODES) offsets[i] = s[threadIdx.x] - v;   // exclusive
  if (threadIdx.x == 255) bsums[blockIdx.x] = s[255];
}

// ---------------- fused: scan of block sums (block 0) + BN-fold into weights (1..96)
__global__ void scan2_fold_kernel(const int* __restrict__ bsums, int* __restrict__ bscan,
                                  int* __restrict__ offsets,
                                  const float* __restrict__ Wq, const float* __restrict__ bq,
                                  const float* __restrict__ Wk, const float* __restrict__ Wv,
                                  const float* __restrict__ gq, const float* __restrict__ bqn,
                                  const float* __restrict__ gk, const float* __restrict__ bkn,
                                  const float* __restrict__ sums,
                                  unsigned short* __restrict__ Wb, float* __restrict__ bias){
  if (blockIdx.x == 0){
    __shared__ int s[256];
    int v = (threadIdx.x < 196) ? bsums[threadIdx.x] : 0;
    s[threadIdx.x] = v;
    __syncthreads();
    for (int d = 1; d < 256; d <<= 1){
      int t = (threadIdx.x >= d) ? s[threadIdx.x - d] : 0;
      __syncthreads();
      s[threadIdx.x] += t;
      __syncthreads();
    }
    if (threadIdx.x < 196) bscan[threadIdx.x] = s[threadIdx.x] - v;
    if (threadIdx.x == 255) offsets[N_NODES] = s[255];
  } else {
    int wave = (blockIdx.x - 1)*4 + (threadIdx.x >> 6);   // 0..383
    int lane = threadIdx.x & 63;
    int m = wave >> 7;          // 0=q,1=v,2=k
    int o = wave & 127;
    const float* Wsrc = (m==0) ? Wq : (m==1) ? Wv : Wk;
    const float* g   = (m==2) ? gk : gq;
    const float* bb  = (m==2) ? bkn : bqn;
    const float* s0  = (m==2) ? (sums + 2*FEATS) : sums;
    const float invN = 1.0f / (float)N_NODES;
    float acc = 0.f;
    unsigned short w2[2];
    int i0 = lane*2;
    #pragma unroll
    for (int t = 0; t < 2; t++){
      int i = i0 + t;
      float mean = s0[i]*invN;
      float var  = s0[FEATS+i]*invN - mean*mean;
      float rstd = rsqrtf(var + 1e-5f);
      float scale = g[i]*rstd;
      float shift = bb[i] - mean*scale;
      float w = Wsrc[o*FEATS + i];
      w2[t] = f2bf(w*scale);
      acc += shift*w;
    }
    unsigned pack = (unsigned)w2[0] | ((unsigned)w2[1] << 16);
    ((unsigned*)Wb)[(m*FEATS*FEATS + o*FEATS + i0) >> 1] = pack;
    #pragma unroll
    for (int off = 1; off < 64; off <<= 1) acc += __shfl_xor(acc, off);
    if (lane == 0) bias[m*FEATS + o] = acc + ((m==0) ? bq[o] : 0.f);
  }
}

__global__ void scan3_kernel(int* __restrict__ offsets, const int* __restrict__ bscan){
  int i = blockIdx.x*256 + threadIdx.x;
  if (i < N_NODES) offsets[i] += bscan[blockIdx.x];
}

__global__ void scatter_kernel(const int* __restrict__ dst, const int* __restrict__ src,
                               const int* __restrict__ offsets,
                               int* __restrict__ cursor, int* __restrict__ src_csr){
  int t = blockIdx.x*256 + threadIdx.x;
  if (t < N_EDGES){
    int d = dst[t];
    int p = atomicAdd(&cursor[d], 1);
    src_csr[offsets[d] + p] = src[t];
  }
}

// ---------------- bf16 MFMA GEMM (3 mats via blockIdx.y); q,v write interleaved qv rows
#define GM 64
__global__ __launch_bounds__(256) void gemm3_kernel(const float* __restrict__ ftq,
                                                    const float* __restrict__ ftk,
                                                    const unsigned short* __restrict__ Wball,
                                                    const float* __restrict__ biasall,
                                                    unsigned short* __restrict__ qv,
                                                    unsigned short* __restrict__ kb){
  int m = blockIdx.y;
  const float* X = (m==2) ? ftk : ftq;
  const unsigned short* Wb = Wball + m*FEATS*FEATS;
  const float* bias = biasall + m*FEATS;
  unsigned short* Out = (m==2) ? kb : (qv + ((m==1) ? 128 : 0));
  const int ostride = (m==2) ? FEATS : 256;

  __shared__ unsigned short As[GM][136];
  __shared__ unsigned short Bs[FEATS][136];
  int tid = threadIdx.x;
  int row0 = blockIdx.x * GM;
  { // stage B (already bf16)
    const unsigned* srcp = (const unsigned*)Wb;
    for (int idx = tid; idx < FEATS*FEATS/2; idx += 256){
      int n = idx >> 6;
      int kk = (idx & 63) * 2;
      *(unsigned*)&Bs[n][kk] = srcp[idx];
    }
  }
  { // stage A with f32->bf16 convert
    for (int idx = tid; idx < GM*FEATS/4; idx += 256){
      int r = idx >> 5;
      int c4 = (idx & 31) * 4;
      int row = row0 + r;
      float4 xv = make_float4(0.f,0.f,0.f,0.f);
      if (row < N_NODES) xv = *(const float4*)(X + (size_t)row*FEATS + c4);
      unsigned p0 = (unsigned)f2bf(xv.x) | ((unsigned)f2bf(xv.y) << 16);
      unsigned p1 = (unsigned)f2bf(xv.z) | ((unsigned)f2bf(xv.w) << 16);
      *(unsigned*)&As[r][c4]   = p0;
      *(unsigned*)&As[r][c4+2] = p1;
    }
  }
  __syncthreads();
  int wave = tid >> 6, lane = tid & 63;
  int r0 = wave * 16;
  int mrow = lane & 15, quad = lane >> 4;
  f32x4 acc[8];
  #pragma unroll
  for (int i = 0; i < 8; i++) acc[i] = (f32x4){0.f,0.f,0.f,0.f};
  #pragma unroll
  for (int kt = 0; kt < 4; kt++){
    int kbk = kt*32 + quad*8;
    bf16x8 a = *(bf16x8*)&As[r0 + mrow][kbk];
    #pragma unroll
    for (int ct = 0; ct < 8; ct++){
      bf16x8 b = *(bf16x8*)&Bs[ct*16 + mrow][kbk];
      acc[ct] = __builtin_amdgcn_mfma_f32_16x16x32_bf16(a, b, acc[ct], 0, 0, 0);
    }
  }
  #pragma unroll
  for (int ct = 0; ct < 8; ct++){
    int col = ct*16 + mrow;
    float bv = bias[col];
    #pragma unroll
    for (int v = 0; v < 4; v++){
      int row = row0 + r0 + quad*4 + v;
      if (row < N_NODES)
        Out[(size_t)row*ostride + col] = f2bf(acc[ct][v] + bv);
    }
  }
}

// ---------------- fused per-dst-node: edge scores + unnormalized agg + divide
// wave = 1 node; 8 groups (g) x 8 heads (h); group g handles edges j = g, g+8, ...
// lane owns head h (16 feats, 32B) of each gathered row. Single pass:
// out[n] = (sum_e ex_e * v[src_e]) / (sum_e ex_e), ex = exp(sum attn*sigmoid(q+k)).
__global__ __launch_bounds__(256) void node_fused_kernel(
    const unsigned short* __restrict__ qv, const unsigned short* __restrict__ kb,
    const float* __restrict__ attn, const int* __restrict__ src_csr,
    const int* __restrict__ offsets, float* __restrict__ out){
  int lane = threadIdx.x & 63;
  int n = blockIdx.x*4 + (threadIdx.x >> 6);
  if (n >= N_NODES) return;
  int h = lane & 7, g = lane >> 3;
  int off0 = offsets[n];
  int deg = offsets[n+1] - off0;
  if (deg == 0){
    ((float2*)(out + (size_t)n*FEATS))[lane] = make_float2(0.f, 0.f);
    return;
  }
  float ar[16], kf[16];
  {
    const uint4* ap = (const uint4*)(attn + h*16);
    uint4 a0 = ap[0], a1 = ap[1], a2 = ap[2], a3 = ap[3];
    ar[0]=__uint_as_float(a0.x); ar[1]=__uint_as_float(a0.y); ar[2]=__uint_as_float(a0.z); ar[3]=__uint_as_float(a0.w);
    ar[4]=__uint_as_float(a1.x); ar[5]=__uint_as_float(a1.y); ar[6]=__uint_as_float(a1.z); ar[7]=__uint_as_float(a1.w);
    ar[8]=__uint_as_float(a2.x); ar[9]=__uint_as_float(a2.y); ar[10]=__uint_as_float(a2.z); ar[11]=__uint_as_float(a2.w);
    ar[12]=__uint_as_float(a3.x); ar[13]=__uint_as_float(a3.y); ar[14]=__uint_as_float(a3.z); ar[15]=__uint_as_float(a3.w);
    const unsigned short* kr = kb + (size_t)n*FEATS + h*16;
    uint4 k0 = *(const uint4*)kr;
    uint4 k1 = *(const uint4*)(kr + 8);
    unpack8(k0, kf); unpack8(k1, kf+8);
  }
  float ssum = 0.f;
  float acc[16];
  #pragma unroll
  for (int i = 0; i < 16; i++) acc[i] = 0.f;
  int s_next = (g < deg) ? src_csr[off0 + g] : 0;
  for (int j = g; j < deg; j += 8){
    int s = s_next;
    if (j + 8 < deg) s_next = src_csr[off0 + j + 8];
    const unsigned short* qr = qv + (size_t)s*256 + h*16;
    uint4 q0 = *(const uint4*)qr;
    uint4 q1 = *(const uint4*)(qr + 8);
    uint4 v0 = *(const uint4*)(qr + 128);     // v interleaved at +256B
    uint4 v1 = *(const uint4*)(qr + 136);
    float qf[16]; unpack8(q0, qf); unpack8(q1, qf+8);
    float t = 0.f;
    #pragma unroll
    for (int i = 0; i < 16; i++){
      float x = qf[i] + kf[i];
      t += ar[i] * __builtin_amdgcn_rcpf(1.f + __expf(-x));
    }
    float ex = __expf(t);     // |t| <= sum|attn| (~25) -> no overflow, max-free softmax
    ssum += ex;
    float vf[16]; unpack8(v0, vf); unpack8(v1, vf+8);
    #pragma unroll
    for (int i = 0; i < 16; i++) acc[i] += ex * vf[i];
  }
  ssum += __shfl_xor(ssum, 8); ssum += __shfl_xor(ssum, 16); ssum += __shfl_xor(ssum, 32);
  #pragma unroll
  for (int i = 0; i < 16; i++){
    acc[i] += __shfl_xor(acc[i], 8);
    acc[i] += __shfl_xor(acc[i], 16);
    acc[i] += __shfl_xor(acc[i], 32);
  }
  if (g == 0){
    float inv_s = 1.f / ssum;
    float4* op = (float4*)(out + (size_t)n*FEATS + h*16);
    op[0] = make_float4(acc[0]*inv_s, acc[1]*inv_s, acc[2]*inv_s, acc[3]*inv_s);
    op[1] = make_float4(acc[4]*inv_s, acc[5]*inv_s, acc[6]*inv_s, acc[7]*inv_s);
    op[2] = make_float4(acc[8]*inv_s, acc[9]*inv_s, acc[10]*inv_s, acc[11]*inv_s);
    op[3] = make_float4(acc[12]*inv_s, acc[13]*inv_s, acc[14]*inv_s, acc[15]*inv_s);
  }
}

extern "C" void kernel_launch(void* const* d_in, const int* in_sizes, int n_in,
                              void* d_out, int out_size, void* d_ws, size_t ws_size,
                              hipStream_t stream){
  (void)in_sizes; (void)n_in; (void)out_size; (void)ws_size;
  const float* ftq  = (const float*)d_in[0];
  const float* ftk  = (const float*)d_in[1];
  const int*   src  = (const int*)d_in[2];
  const int*   dst  = (const int*)d_in[3];
  const float* Wq   = (const float*)d_in[4];
  const float* bq   = (const float*)d_in[5];
  const float* Wk   = (const float*)d_in[6];
  const float* Wv   = (const float*)d_in[7];
  const float* attn = (const float*)d_in[8];
  const float* gq   = (const float*)d_in[9];
  const float* bqn  = (const float*)d_in[10];
  const float* gk   = (const float*)d_in[11];
  const float* bkn  = (const float*)d_in[12];

  char* ws = (char*)d_ws;
  int*   counts  = (int*)(ws + 0);            // 200000 B
  int*   cursor  = (int*)(ws + 200000);       // 200000 B
  float* sums    = (float*)(ws + 400000);     // 2048 B (zero region ends 402048)
  int*   offsets = (int*)(ws + 402048);       // 200004 B -> pad 602064
  int*   bsums   = (int*)(ws + 602064);       // 1024 B
  int*   bscan   = (int*)(ws + 603088);       // 1024 B
  int*   src_csr = (int*)(ws + 604112);       // 3.2e6 B
  unsigned short* Wb   = (unsigned short*)(ws + 3804112);  // 98304 B
  float* biasf   = (float*)(ws + 3902416);    // 1536 B
  unsigned short* qv = (unsigned short*)(ws + 3903952);    // 50000*256*2 = 25.6e6 B
  unsigned short* kb = qv + (size_t)N_NODES*256;           // 12.8e6 B
  float* out = (float*)d_out;

  hipMemsetAsync(ws, 0, 402048, stream);  // counts, cursor, bn sums

  hipLaunchKernelGGL(stats_hist_kernel, dim3(768), dim3(256), 0, stream,
                     ftq, ftk, sums, dst, counts);
  hipLaunchKernelGGL(scan1_kernel, dim3(196), dim3(256), 0, stream, counts, offsets, bsums);
  hipLaunchKernelGGL(scan2_fold_kernel, dim3(97), dim3(256), 0, stream,
                     bsums, bscan, offsets,
                     Wq, bq, Wk, Wv, gq, bqn, gk, bkn, sums, Wb, biasf);
  hipLaunchKernelGGL(scan3_kernel, dim3(196), dim3(256), 0, stream, offsets, bscan);
  hipLaunchKernelGGL(scatter_kernel, dim3((N_EDGES+255)/256), dim3(256), 0, stream,
                     dst, src, offsets, cursor, src_csr);
  hipLaunchKernelGGL(gemm3_kernel, dim3((N_NODES+GM-1)/GM, 3), dim3(256), 0, stream,
                     ftq, ftk, Wb, biasf, qv, kb);
  hipLaunchKernelGGL(node_fused_kernel, dim3((N_NODES+3)/4), dim3(256), 0, stream,
                     qv, kb, attn, src_csr, offsets, out);
}